// Round 15
// baseline (401.430 us; speedup 1.0000x reference)
//
#include <hip/hip_runtime.h>
#include <hip/hip_bf16.h>
#include <cstdint>
#include <cstddef>

#define Bc 8
#define Lc 2048
#define Dc 1152
#define STRIDE 2080
#define G 16
#define NCHUNK 18            // e-chunks of 64

// ---- workspace layout (bytes) ----
#define WCV_OFF   0u
#define PART_OFF  10616832u
#define PV_OFF    17760256u
#define BPOS_OFF  17826816u
#define NB_OFF    17893376u

using bf16x8 = __attribute__((ext_vector_type(8))) short;
using f32x4  = __attribute__((ext_vector_type(4))) float;
#define MFMA(a, b, c) __builtin_amdgcn_mfma_f32_16x16x32_bf16(a, b, c, 0, 0, 0)

__device__ __forceinline__ void gld16(const void* g, void* l) {
    __builtin_amdgcn_global_load_lds(
        (const __attribute__((address_space(1))) void*)(g),
        (__attribute__((address_space(3))) void*)(l), 16, 0, 0);
}

__device__ __forceinline__ unsigned short bf_hi(float x) {
    __hip_bfloat16 h = __float2bfloat16(x);
    return *reinterpret_cast<unsigned short*>(&h);
}
__device__ __forceinline__ float bf_f(unsigned short u) {
    __hip_bfloat16 h; *reinterpret_cast<unsigned short*>(&h) = u;
    return __bfloat162float(h);
}

// ---------------- Kernel 0: fp32 -> bf16 hi/lo split, staged layout ----------------
__global__ __launch_bounds__(256) void k0_convert(
    const float* __restrict__ H, const float* __restrict__ Wq,
    const float* __restrict__ Wk, char* __restrict__ Hcv, char* __restrict__ Wcv)
{
    int idx = blockIdx.x * 256 + threadIdx.x;
    if (idx >= (16384 + 2304) * 144) return;
    int cchunk = idx & 3;
    int ks = (idx >> 2) % 36;
    int row = idx / 144;
    const float* src;
    char* dst;
    if (row < 16384) {
        src = H + (size_t)row * Dc;
        dst = Hcv + ((size_t)row * 36 + ks) * 128;
    } else {
        int e = row - 16384;
        src = (e < Dc) ? (Wq + (size_t)e * Dc) : (Wk + (size_t)(e - Dc) * Dc);
        dst = Wcv + ((size_t)e * 36 + ks) * 128;
    }
    const float* s = src + ks * 32 + cchunk * 8;
    unsigned int hw0 = 0, hw1 = 0, hw2 = 0, hw3 = 0;
    unsigned int lw0 = 0, lw1 = 0, lw2 = 0, lw3 = 0;
    #define CV(i, HW, LW, SH)                                                  \
    {                                                                          \
        float x = s[i];                                                        \
        unsigned short h = bf_hi(x);                                           \
        unsigned short lo = bf_hi(x - bf_f(h));                                \
        HW |= ((unsigned int)h) << (SH);                                       \
        LW |= ((unsigned int)lo) << (SH);                                      \
    }
    CV(0, hw0, lw0, 0) CV(1, hw0, lw0, 16) CV(2, hw1, lw1, 0) CV(3, hw1, lw1, 16)
    CV(4, hw2, lw2, 0) CV(5, hw2, lw2, 16) CV(6, hw3, lw3, 0) CV(7, hw3, lw3, 16)
    #undef CV
    uint4 hv; hv.x = hw0; hv.y = hw1; hv.z = hw2; hv.w = hw3;
    uint4 lv; lv.x = lw0; lv.y = lw1; lv.z = lw2; lv.w = lw3;
    *(uint4*)(dst + cchunk * 16) = hv;
    *(uint4*)(dst + 64 + cchunk * 16) = lv;
}

// ---------------- Kernel 1: 3-product bf16-split MFMA GEMM (r11, 216 us) ----------------
// Best-measured structure: 0.5 reads/MFMA, 68 VGPR + 64 AGPR, ~9.5 waves/CU.
// r12 (dbuf), r13 (8-wave), r14 (R=4) all regressed: any LDS-traffic savings
// were repaid in occupancy. Within 5% of the LDS-traffic wall -- frozen.
__global__ __launch_bounds__(256, 2) void k1_mfma(
    const char* __restrict__ Hcv, const char* __restrict__ Wcv,
    float* __restrict__ partial)
{
    __shared__ __align__(16) char LdsB[32896];   // H 129*128=16512 | W 128*128=16384
    const int tid = threadIdx.x;
    const int bid = blockIdx.x;
    const int x = bid & 7;               // XCD-local remap
    const int r = bid >> 3;
    const int g = x + 8 * (r / 18);
    const int j = r % 18;
    const int batch = g >> 4;
    const int mt = g & 15;
    const int t0 = 1 + mt * 128;
    const int rowbase = batch * Lc + t0 - 1;
    const int rowmax = batch * Lc + (Lc - 1);

    const char *hp0, *hpt, *wp0;
    {
        int row = tid >> 3;
        int ch = (tid & 7) ^ (row & 7);
        hp0 = Hcv + (size_t)(rowbase + row) * 4608 + (ch << 4);
        int gr2 = rowbase + 128; if (gr2 > rowmax) gr2 = rowmax;
        hpt = Hcv + (size_t)gr2 * 4608 + ((tid & 7) << 4);
        wp0 = Wcv + (size_t)(j * 64 + row) * 4608 + (ch << 4);
    }

    const int l = tid & 63;
    const int w = tid >> 6;
    const int rl = l & 15;
    const int c = l >> 4;

    const int sA = c ^ (rl & 7);
    const int sB = c ^ ((rl + 1) & 7);
    const int offAh = rl * 128 + (sA << 4);
    const int offAl = rl * 128 + ((sA ^ 4) << 4);
    const int offBh = (rl + 1) * 128 + (sB << 4);
    const int offBl = (rl + 1) * 128 + ((sB ^ 4) << 4);
    const char* Wb = LdsB + 16512;

    f32x4 q00{0,0,0,0}, q01{0,0,0,0}, q02{0,0,0,0}, q03{0,0,0,0};
    f32x4 q10{0,0,0,0}, q11{0,0,0,0}, q12{0,0,0,0}, q13{0,0,0,0};
    f32x4 k00{0,0,0,0}, k01{0,0,0,0}, k02{0,0,0,0}, k03{0,0,0,0};
    f32x4 k10{0,0,0,0}, k11{0,0,0,0}, k12{0,0,0,0}, k13{0,0,0,0};

    for (int ks = 0; ks < 36; ++ks) {
        gld16(hp0,           LdsB + tid * 16);
        gld16(hp0 + 147456,  LdsB + (tid + 256) * 16);
        gld16(hp0 + 294912,  LdsB + (tid + 512) * 16);
        gld16(hp0 + 442368,  LdsB + (tid + 768) * 16);
        if (tid < 8) gld16(hpt, LdsB + (1024 + tid) * 16);
        gld16(wp0,           LdsB + 16512 + tid * 16);
        gld16(wp0 + 147456,  LdsB + 16512 + (tid + 256) * 16);
        gld16(wp0 + 5308416, LdsB + 16512 + (tid + 512) * 16);
        gld16(wp0 + 5455872, LdsB + 16512 + (tid + 768) * 16);
        hp0 += 128; hpt += 128; wp0 += 128;
        __syncthreads();

        const char* hm0 = LdsB + (2 * w) * 2048;
        const char* hm1 = LdsB + (2 * w + 1) * 2048;
        bf16x8 a0h = *(const bf16x8*)(hm0 + offAh);
        bf16x8 a0l = *(const bf16x8*)(hm0 + offAl);
        bf16x8 b0h = *(const bf16x8*)(hm0 + offBh);
        bf16x8 b0l = *(const bf16x8*)(hm0 + offBl);
        bf16x8 a1h = *(const bf16x8*)(hm1 + offAh);
        bf16x8 a1l = *(const bf16x8*)(hm1 + offAl);
        bf16x8 b1h = *(const bf16x8*)(hm1 + offBh);
        bf16x8 b1l = *(const bf16x8*)(hm1 + offBl);

        #define FSTEP(f, QA0, QA1, KA0, KA1)                                   \
        {                                                                      \
            const char* wqb = Wb + (f) * 2048;                                 \
            bf16x8 wh = *(const bf16x8*)(wqb + offAh);                         \
            bf16x8 wl = *(const bf16x8*)(wqb + offAl);                         \
            QA0 = MFMA(a0h, wh, QA0); QA0 = MFMA(a0h, wl, QA0);                \
            QA0 = MFMA(a0l, wh, QA0);                                          \
            QA1 = MFMA(a1h, wh, QA1); QA1 = MFMA(a1h, wl, QA1);                \
            QA1 = MFMA(a1l, wh, QA1);                                          \
            const char* wkb = Wb + 8192 + (f) * 2048;                          \
            bf16x8 vh = *(const bf16x8*)(wkb + offAh);                         \
            bf16x8 vl = *(const bf16x8*)(wkb + offAl);                         \
            KA0 = MFMA(b0h, vh, KA0); KA0 = MFMA(b0h, vl, KA0);                \
            KA0 = MFMA(b0l, vh, KA0);                                          \
            KA1 = MFMA(b1h, vh, KA1); KA1 = MFMA(b1h, vl, KA1);                \
            KA1 = MFMA(b1l, vh, KA1);                                          \
            __builtin_amdgcn_sched_barrier(0);                                 \
        }
        FSTEP(0, q00, q10, k00, k10)
        FSTEP(1, q01, q11, k01, k11)
        FSTEP(2, q02, q12, k02, k12)
        FSTEP(3, q03, q13, k03, k13)
        #undef FSTEP
        __syncthreads();
    }

    #define EMIT(QA, QB, QC, QD, KA, KB, KC, KD, TROW)                         \
    {                                                                          \
        float qq = (QA)*(QA) + (QB)*(QB) + (QC)*(QC) + (QD)*(QD);              \
        float kk = (KA)*(KA) + (KB)*(KB) + (KC)*(KC) + (KD)*(KD);              \
        float qk = (QA)*(KA) + (QB)*(KB) + (QC)*(KC) + (QD)*(KD);              \
        qq += __shfl_xor(qq, 1, 64); qq += __shfl_xor(qq, 2, 64);              \
        qq += __shfl_xor(qq, 4, 64); qq += __shfl_xor(qq, 8, 64);              \
        kk += __shfl_xor(kk, 1, 64); kk += __shfl_xor(kk, 2, 64);              \
        kk += __shfl_xor(kk, 4, 64); kk += __shfl_xor(kk, 8, 64);              \
        qk += __shfl_xor(qk, 1, 64); qk += __shfl_xor(qk, 2, 64);              \
        qk += __shfl_xor(qk, 4, 64); qk += __shfl_xor(qk, 8, 64);              \
        if (rl == 0) {                                                         \
            int t = t0 + (TROW);                                               \
            if (t < Lc) {                                                      \
                size_t pidx = (((size_t)j * Bc + batch) * Lc + t) * 3;         \
                partial[pidx] = qq; partial[pidx + 1] = kk;                    \
                partial[pidx + 2] = qk;                                        \
            }                                                                  \
        }                                                                      \
    }
    EMIT(q00[0], q01[0], q02[0], q03[0], k00[0], k01[0], k02[0], k03[0], 32*w + c*4 + 0)
    EMIT(q00[1], q01[1], q02[1], q03[1], k00[1], k01[1], k02[1], k03[1], 32*w + c*4 + 1)
    EMIT(q00[2], q01[2], q02[2], q03[2], k00[2], k01[2], k02[2], k03[2], 32*w + c*4 + 2)
    EMIT(q00[3], q01[3], q02[3], q03[3], k00[3], k01[3], k02[3], k03[3], 32*w + c*4 + 3)
    EMIT(q10[0], q11[0], q12[0], q13[0], k10[0], k11[0], k12[0], k13[0], 32*w + 16 + c*4 + 0)
    EMIT(q10[1], q11[1], q12[1], q13[1], k10[1], k11[1], k12[1], k13[1], 32*w + 16 + c*4 + 1)
    EMIT(q10[2], q11[2], q12[2], q13[2], k10[2], k11[2], k12[2], k13[2], 32*w + 16 + c*4 + 2)
    EMIT(q10[3], q11[3], q12[3], q13[3], k10[3], k11[3], k12[3], k13[3], 32*w + 16 + c*4 + 3)
    #undef EMIT
}

// ---------------- Kernel 2: chunk-reduce -> bl (in LDS) + boundary + compaction ----------------
// Fused k1b+k2: one block per batch. Each thread reduces the 18 e-chunk
// partials for its 8 positions, forms bl, decides, scans, emits compacted
// (t, p) pairs. Saves a launch + the bl global round-trip.
__global__ __launch_bounds__(256) void k2_boundary(
    const float* __restrict__ partial, const float* __restrict__ ltemp,
    const float* __restrict__ bbias, const int* __restrict__ mask,
    float* __restrict__ pv, int* __restrict__ bpos, int* __restrict__ nb)
{
    int b = blockIdx.x;
    int tid = threadIdx.x;
    const int* mb = mask + b * Lc;
    float T = expf(ltemp[0]);
    T = fminf(fmaxf(T, 0.1f), 10.0f);
    float bias = bbias[0];

    float blv[8]; int f[8];
    int t0 = tid * 8;
    int s = 0;
    #pragma unroll
    for (int i = 0; i < 8; ++i) {
        int t = t0 + i;
        float v;
        if (t == 0) {
            v = 10.0f;
        } else {
            float qq = 0.f, kk = 0.f, qk = 0.f;
            #pragma unroll
            for (int cn = 0; cn < NCHUNK; ++cn) {
                size_t p = (((size_t)cn * Bc + b) * Lc + t) * 3;
                qq += partial[p];
                kk += partial[p + 1];
                qk += partial[p + 2];
            }
            float den = fmaxf(sqrtf(qq), 1e-12f) * fmaxf(sqrtf(kk), 1e-12f);
            v = (1.0f - qk / den) * T + bias;
        }
        blv[i] = v;
        f[i] = (v > 0.0f && mb[t] != 0) ? 1 : 0;
        s += f[i];
    }
    int lane = tid & 63, wv = tid >> 6;
    int sc = s;
    #pragma unroll
    for (int off = 1; off < 64; off <<= 1) {
        int o = __shfl_up(sc, off, 64);
        if (lane >= off) sc += o;
    }
    __shared__ int wsums[4];
    if (lane == 63) wsums[wv] = sc;
    __syncthreads();
    int woff = 0;
    #pragma unroll
    for (int w2 = 0; w2 < 4; ++w2) woff += (w2 < wv) ? wsums[w2] : 0;
    int excl = woff + sc - s;
    int total = wsums[0] + wsums[1] + wsums[2] + wsums[3];

    float* pvb = pv + b * STRIDE;
    int* bpb = bpos + b * STRIDE;
    int r = excl;
    #pragma unroll
    for (int i = 0; i < 8; ++i) {
        if (f[i]) {
            int t = t0 + i;
            float p;
            if (t == 0) {
                p = 1.0f;
            } else {
                p = 1.0f / (1.0f + expf(-2.0f * blv[i]));
                p = fminf(fmaxf(p, 1e-4f), 1.0f - 1e-4f);
            }
            bpb[r] = t;
            pvb[r] = p;
            r += 1;
        }
    }
    if (tid == 0) nb[b] = total;
    for (int q = total + tid; q < STRIDE; q += 256) { bpb[q] = Lc; pvb[q] = 0.0f; }
}

// ---------------- Kernel 3: EMA over boundary tokens + span expansion ----------------
// G=16 prefetch: k3 is latency-bound (time ~ (n/G) x HBM latency); deeper
// groups halve the serial latency count. Padding covers reads to 2064<2080.
__global__ __launch_bounds__(64) void k3_ema(
    const float* __restrict__ H, const float* __restrict__ pv,
    const int* __restrict__ bpos, const int* __restrict__ nb,
    float* __restrict__ out)
{
    int b = blockIdx.x;
    int ch = blockIdx.y * 64 + threadIdx.x;
    const float* Hb = H + (size_t)b * Lc * Dc + ch;
    float* Ob = out + (size_t)b * Lc * Dc + ch;
    const float* pvb = pv + b * STRIDE;
    const int* bpb = bpos + b * STRIDE;
    int n = nb[b];
    int ng = (n + G - 1) / G;

    float xA[G], pA[G]; int tA[G + 1];
    #pragma unroll
    for (int i = 0; i < G; ++i) {
        int t = bpb[i];
        tA[i] = t;
        pA[i] = pvb[i];
        xA[i] = (t < Lc) ? Hb[(size_t)t * Dc] : 0.0f;
    }
    tA[G] = bpb[G];

    float h = 0.0f;
    for (int g = 0; g < ng; ++g) {
        int nbase = (g + 1) * G;
        float xB[G], pB[G]; int tB[G + 1];
        #pragma unroll
        for (int i = 0; i < G; ++i) {
            int t = bpb[nbase + i];
            tB[i] = t;
            pB[i] = pvb[nbase + i];
            xB[i] = (t < Lc) ? Hb[(size_t)t * Dc] : 0.0f;
        }
        tB[G] = bpb[nbase + G];
        #pragma unroll
        for (int i = 0; i < G; ++i) {
            h = (1.0f - pA[i]) * h + pA[i] * xA[i];
            int te = tA[i + 1];
            for (int tt = tA[i]; tt < te; ++tt) Ob[(size_t)tt * Dc] = h;
        }
        #pragma unroll
        for (int i = 0; i < G; ++i) { xA[i] = xB[i]; pA[i] = pB[i]; tA[i] = tB[i]; }
        tA[G] = tB[G];
    }
}

extern "C" void kernel_launch(void* const* d_in, const int* in_sizes, int n_in,
                              void* d_out, int out_size, void* d_ws, size_t ws_size,
                              hipStream_t stream)
{
    const float* H  = (const float*)d_in[0];
    const float* Wq = (const float*)d_in[1];
    const float* Wk = (const float*)d_in[2];
    const float* lt = (const float*)d_in[3];
    const float* bb = (const float*)d_in[4];
    const int* mask = (const int*)d_in[5];
    float* out = (float*)d_out;

    char* ws = (char*)d_ws;
    char*  Hcv  = (char*)d_out;                  // staging in d_out; K3 overwrites
    char*  Wcv  = ws + WCV_OFF;
    float* part = (float*)(ws + PART_OFF);
    float* pv   = (float*)(ws + PV_OFF);
    int*   bpos = (int*)(ws + BPOS_OFF);
    int*   nbp  = (int*)(ws + NB_OFF);

    hipLaunchKernelGGL(k0_convert, dim3(((16384 + 2304) * 144 + 255) / 256),
                       dim3(256), 0, stream, H, Wq, Wk, Hcv, Wcv);
    hipLaunchKernelGGL(k1_mfma, dim3(NCHUNK * 128), dim3(256), 0, stream,
                       Hcv, Wcv, part);
    hipLaunchKernelGGL(k2_boundary, dim3(Bc), dim3(256), 0, stream,
                       part, lt, bb, mask, pv, bpos, nbp);
    hipLaunchKernelGGL(k3_ema, dim3(Bc, 18), dim3(64), 0, stream,
                       H, pv, bpos, nbp, out);
}

// Round 16
// 379.736 us; speedup vs baseline: 1.0571x; 1.0571x over previous
//
#include <hip/hip_runtime.h>
#include <hip/hip_bf16.h>
#include <cstdint>
#include <cstddef>

#define Bc 8
#define Lc 2048
#define Dc 1152
#define STRIDE 2080
#define G 8
#define NCHUNK 18            // e-chunks of 64

// ---- workspace layout (bytes) ----
#define WCV_OFF   0u
#define PART_OFF  10616832u
#define PV_OFF    17760256u
#define BPOS_OFF  17826816u
#define NB_OFF    17893376u

using bf16x8 = __attribute__((ext_vector_type(8))) short;
using f32x4  = __attribute__((ext_vector_type(4))) float;
#define MFMA(a, b, c) __builtin_amdgcn_mfma_f32_16x16x32_bf16(a, b, c, 0, 0, 0)

__device__ __forceinline__ void gld16(const void* g, void* l) {
    __builtin_amdgcn_global_load_lds(
        (const __attribute__((address_space(1))) void*)(g),
        (__attribute__((address_space(3))) void*)(l), 16, 0, 0);
}

__device__ __forceinline__ unsigned short bf_hi(float x) {
    __hip_bfloat16 h = __float2bfloat16(x);
    return *reinterpret_cast<unsigned short*>(&h);
}
__device__ __forceinline__ float bf_f(unsigned short u) {
    __hip_bfloat16 h; *reinterpret_cast<unsigned short*>(&h) = u;
    return __bfloat162float(h);
}

// ---------------- Kernel 0: fp32 -> bf16 hi/lo split, staged layout ----------------
__global__ __launch_bounds__(256) void k0_convert(
    const float* __restrict__ H, const float* __restrict__ Wq,
    const float* __restrict__ Wk, char* __restrict__ Hcv, char* __restrict__ Wcv)
{
    int idx = blockIdx.x * 256 + threadIdx.x;
    if (idx >= (16384 + 2304) * 144) return;
    int cchunk = idx & 3;
    int ks = (idx >> 2) % 36;
    int row = idx / 144;
    const float* src;
    char* dst;
    if (row < 16384) {
        src = H + (size_t)row * Dc;
        dst = Hcv + ((size_t)row * 36 + ks) * 128;
    } else {
        int e = row - 16384;
        src = (e < Dc) ? (Wq + (size_t)e * Dc) : (Wk + (size_t)(e - Dc) * Dc);
        dst = Wcv + ((size_t)e * 36 + ks) * 128;
    }
    const float* s = src + ks * 32 + cchunk * 8;
    unsigned int hw0 = 0, hw1 = 0, hw2 = 0, hw3 = 0;
    unsigned int lw0 = 0, lw1 = 0, lw2 = 0, lw3 = 0;
    #define CV(i, HW, LW, SH)                                                  \
    {                                                                          \
        float x = s[i];                                                        \
        unsigned short h = bf_hi(x);                                           \
        unsigned short lo = bf_hi(x - bf_f(h));                                \
        HW |= ((unsigned int)h) << (SH);                                       \
        LW |= ((unsigned int)lo) << (SH);                                      \
    }
    CV(0, hw0, lw0, 0) CV(1, hw0, lw0, 16) CV(2, hw1, lw1, 0) CV(3, hw1, lw1, 16)
    CV(4, hw2, lw2, 0) CV(5, hw2, lw2, 16) CV(6, hw3, lw3, 0) CV(7, hw3, lw3, 16)
    #undef CV
    uint4 hv; hv.x = hw0; hv.y = hw1; hv.z = hw2; hv.w = hw3;
    uint4 lv; lv.x = lw0; lv.y = lw1; lv.z = lw2; lv.w = lw3;
    *(uint4*)(dst + cchunk * 16) = hv;
    *(uint4*)(dst + 64 + cchunk * 16) = lv;
}

// ---------------- Kernel 1: 3-product bf16-split MFMA GEMM (r11, 216 us) ----------------
// Best-measured structure: 0.5 reads/MFMA, 68 VGPR + 64 AGPR, ~9.5 waves/CU.
// r12 (dbuf), r13 (8-wave), r14 (R=4) all regressed: any LDS-traffic savings
// were repaid in occupancy. Within ~5% of the LDS-traffic wall -- frozen.
__global__ __launch_bounds__(256, 2) void k1_mfma(
    const char* __restrict__ Hcv, const char* __restrict__ Wcv,
    float* __restrict__ partial)
{
    __shared__ __align__(16) char LdsB[32896];   // H 129*128=16512 | W 128*128=16384
    const int tid = threadIdx.x;
    const int bid = blockIdx.x;
    const int x = bid & 7;               // XCD-local remap
    const int r = bid >> 3;
    const int g = x + 8 * (r / 18);
    const int j = r % 18;
    const int batch = g >> 4;
    const int mt = g & 15;
    const int t0 = 1 + mt * 128;
    const int rowbase = batch * Lc + t0 - 1;
    const int rowmax = batch * Lc + (Lc - 1);

    const char *hp0, *hpt, *wp0;
    {
        int row = tid >> 3;
        int ch = (tid & 7) ^ (row & 7);
        hp0 = Hcv + (size_t)(rowbase + row) * 4608 + (ch << 4);
        int gr2 = rowbase + 128; if (gr2 > rowmax) gr2 = rowmax;
        hpt = Hcv + (size_t)gr2 * 4608 + ((tid & 7) << 4);
        wp0 = Wcv + (size_t)(j * 64 + row) * 4608 + (ch << 4);
    }

    const int l = tid & 63;
    const int w = tid >> 6;
    const int rl = l & 15;
    const int c = l >> 4;

    const int sA = c ^ (rl & 7);
    const int sB = c ^ ((rl + 1) & 7);
    const int offAh = rl * 128 + (sA << 4);
    const int offAl = rl * 128 + ((sA ^ 4) << 4);
    const int offBh = (rl + 1) * 128 + (sB << 4);
    const int offBl = (rl + 1) * 128 + ((sB ^ 4) << 4);
    const char* Wb = LdsB + 16512;

    f32x4 q00{0,0,0,0}, q01{0,0,0,0}, q02{0,0,0,0}, q03{0,0,0,0};
    f32x4 q10{0,0,0,0}, q11{0,0,0,0}, q12{0,0,0,0}, q13{0,0,0,0};
    f32x4 k00{0,0,0,0}, k01{0,0,0,0}, k02{0,0,0,0}, k03{0,0,0,0};
    f32x4 k10{0,0,0,0}, k11{0,0,0,0}, k12{0,0,0,0}, k13{0,0,0,0};

    for (int ks = 0; ks < 36; ++ks) {
        gld16(hp0,           LdsB + tid * 16);
        gld16(hp0 + 147456,  LdsB + (tid + 256) * 16);
        gld16(hp0 + 294912,  LdsB + (tid + 512) * 16);
        gld16(hp0 + 442368,  LdsB + (tid + 768) * 16);
        if (tid < 8) gld16(hpt, LdsB + (1024 + tid) * 16);
        gld16(wp0,           LdsB + 16512 + tid * 16);
        gld16(wp0 + 147456,  LdsB + 16512 + (tid + 256) * 16);
        gld16(wp0 + 5308416, LdsB + 16512 + (tid + 512) * 16);
        gld16(wp0 + 5455872, LdsB + 16512 + (tid + 768) * 16);
        hp0 += 128; hpt += 128; wp0 += 128;
        __syncthreads();

        const char* hm0 = LdsB + (2 * w) * 2048;
        const char* hm1 = LdsB + (2 * w + 1) * 2048;
        bf16x8 a0h = *(const bf16x8*)(hm0 + offAh);
        bf16x8 a0l = *(const bf16x8*)(hm0 + offAl);
        bf16x8 b0h = *(const bf16x8*)(hm0 + offBh);
        bf16x8 b0l = *(const bf16x8*)(hm0 + offBl);
        bf16x8 a1h = *(const bf16x8*)(hm1 + offAh);
        bf16x8 a1l = *(const bf16x8*)(hm1 + offAl);
        bf16x8 b1h = *(const bf16x8*)(hm1 + offBh);
        bf16x8 b1l = *(const bf16x8*)(hm1 + offBl);

        #define FSTEP(f, QA0, QA1, KA0, KA1)                                   \
        {                                                                      \
            const char* wqb = Wb + (f) * 2048;                                 \
            bf16x8 wh = *(const bf16x8*)(wqb + offAh);                         \
            bf16x8 wl = *(const bf16x8*)(wqb + offAl);                         \
            QA0 = MFMA(a0h, wh, QA0); QA0 = MFMA(a0h, wl, QA0);                \
            QA0 = MFMA(a0l, wh, QA0);                                          \
            QA1 = MFMA(a1h, wh, QA1); QA1 = MFMA(a1h, wl, QA1);                \
            QA1 = MFMA(a1l, wh, QA1);                                          \
            const char* wkb = Wb + 8192 + (f) * 2048;                          \
            bf16x8 vh = *(const bf16x8*)(wkb + offAh);                         \
            bf16x8 vl = *(const bf16x8*)(wkb + offAl);                         \
            KA0 = MFMA(b0h, vh, KA0); KA0 = MFMA(b0h, vl, KA0);                \
            KA0 = MFMA(b0l, vh, KA0);                                          \
            KA1 = MFMA(b1h, vh, KA1); KA1 = MFMA(b1h, vl, KA1);                \
            KA1 = MFMA(b1l, vh, KA1);                                          \
            __builtin_amdgcn_sched_barrier(0);                                 \
        }
        FSTEP(0, q00, q10, k00, k10)
        FSTEP(1, q01, q11, k01, k11)
        FSTEP(2, q02, q12, k02, k12)
        FSTEP(3, q03, q13, k03, k13)
        #undef FSTEP
        __syncthreads();
    }

    #define EMIT(QA, QB, QC, QD, KA, KB, KC, KD, TROW)                         \
    {                                                                          \
        float qq = (QA)*(QA) + (QB)*(QB) + (QC)*(QC) + (QD)*(QD);              \
        float kk = (KA)*(KA) + (KB)*(KB) + (KC)*(KC) + (KD)*(KD);              \
        float qk = (QA)*(KA) + (QB)*(KB) + (QC)*(KC) + (QD)*(KD);              \
        qq += __shfl_xor(qq, 1, 64); qq += __shfl_xor(qq, 2, 64);              \
        qq += __shfl_xor(qq, 4, 64); qq += __shfl_xor(qq, 8, 64);              \
        kk += __shfl_xor(kk, 1, 64); kk += __shfl_xor(kk, 2, 64);              \
        kk += __shfl_xor(kk, 4, 64); kk += __shfl_xor(kk, 8, 64);              \
        qk += __shfl_xor(qk, 1, 64); qk += __shfl_xor(qk, 2, 64);              \
        qk += __shfl_xor(qk, 4, 64); qk += __shfl_xor(qk, 8, 64);              \
        if (rl == 0) {                                                         \
            int t = t0 + (TROW);                                               \
            if (t < Lc) {                                                      \
                size_t pidx = (((size_t)j * Bc + batch) * Lc + t) * 3;         \
                partial[pidx] = qq; partial[pidx + 1] = kk;                    \
                partial[pidx + 2] = qk;                                        \
            }                                                                  \
        }                                                                      \
    }
    EMIT(q00[0], q01[0], q02[0], q03[0], k00[0], k01[0], k02[0], k03[0], 32*w + c*4 + 0)
    EMIT(q00[1], q01[1], q02[1], q03[1], k00[1], k01[1], k02[1], k03[1], 32*w + c*4 + 1)
    EMIT(q00[2], q01[2], q02[2], q03[2], k00[2], k01[2], k02[2], k03[2], 32*w + c*4 + 2)
    EMIT(q00[3], q01[3], q02[3], q03[3], k00[3], k01[3], k02[3], k03[3], 32*w + c*4 + 3)
    EMIT(q10[0], q11[0], q12[0], q13[0], k10[0], k11[0], k12[0], k13[0], 32*w + 16 + c*4 + 0)
    EMIT(q10[1], q11[1], q12[1], q13[1], k10[1], k11[1], k12[1], k13[1], 32*w + 16 + c*4 + 1)
    EMIT(q10[2], q11[2], q12[2], q13[2], k10[2], k11[2], k12[2], k13[2], 32*w + 16 + c*4 + 2)
    EMIT(q10[3], q11[3], q12[3], q13[3], k10[3], k11[3], k12[3], k13[3], 32*w + 16 + c*4 + 3)
    #undef EMIT
}

// ---------------- Kernel 2: chunk-reduce -> bl + boundary + compaction (fused) ----------------
__global__ __launch_bounds__(256) void k2_boundary(
    const float* __restrict__ partial, const float* __restrict__ ltemp,
    const float* __restrict__ bbias, const int* __restrict__ mask,
    float* __restrict__ pv, int* __restrict__ bpos, int* __restrict__ nb)
{
    int b = blockIdx.x;
    int tid = threadIdx.x;
    const int* mb = mask + b * Lc;
    float T = expf(ltemp[0]);
    T = fminf(fmaxf(T, 0.1f), 10.0f);
    float bias = bbias[0];

    float blv[8]; int f[8];
    int t0 = tid * 8;
    int s = 0;
    #pragma unroll
    for (int i = 0; i < 8; ++i) {
        int t = t0 + i;
        float v;
        if (t == 0) {
            v = 10.0f;
        } else {
            float qq = 0.f, kk = 0.f, qk = 0.f;
            #pragma unroll
            for (int cn = 0; cn < NCHUNK; ++cn) {
                size_t p = (((size_t)cn * Bc + b) * Lc + t) * 3;
                qq += partial[p];
                kk += partial[p + 1];
                qk += partial[p + 2];
            }
            float den = fmaxf(sqrtf(qq), 1e-12f) * fmaxf(sqrtf(kk), 1e-12f);
            v = (1.0f - qk / den) * T + bias;
        }
        blv[i] = v;
        f[i] = (v > 0.0f && mb[t] != 0) ? 1 : 0;
        s += f[i];
    }
    int lane = tid & 63, wv = tid >> 6;
    int sc = s;
    #pragma unroll
    for (int off = 1; off < 64; off <<= 1) {
        int o = __shfl_up(sc, off, 64);
        if (lane >= off) sc += o;
    }
    __shared__ int wsums[4];
    if (lane == 63) wsums[wv] = sc;
    __syncthreads();
    int woff = 0;
    #pragma unroll
    for (int w2 = 0; w2 < 4; ++w2) woff += (w2 < wv) ? wsums[w2] : 0;
    int excl = woff + sc - s;
    int total = wsums[0] + wsums[1] + wsums[2] + wsums[3];

    float* pvb = pv + b * STRIDE;
    int* bpb = bpos + b * STRIDE;
    int r = excl;
    #pragma unroll
    for (int i = 0; i < 8; ++i) {
        if (f[i]) {
            int t = t0 + i;
            float p;
            if (t == 0) {
                p = 1.0f;
            } else {
                p = 1.0f / (1.0f + expf(-2.0f * blv[i]));
                p = fminf(fmaxf(p, 1e-4f), 1.0f - 1e-4f);
            }
            bpb[r] = t;
            pvb[r] = p;
            r += 1;
        }
    }
    if (tid == 0) nb[b] = total;
    for (int q = total + tid; q < STRIDE; q += 256) { bpb[q] = Lc; pvb[q] = 0.0f; }
}

// ---------------- Kernel 3: EMA over boundary tokens + span expansion ----------------
// G=8 (proven; r15's G=16 spilled -> +36 us). grid (8,18)x64 threads.
__global__ __launch_bounds__(64) void k3_ema(
    const float* __restrict__ H, const float* __restrict__ pv,
    const int* __restrict__ bpos, const int* __restrict__ nb,
    float* __restrict__ out)
{
    int b = blockIdx.x;
    int ch = blockIdx.y * 64 + threadIdx.x;
    const float* Hb = H + (size_t)b * Lc * Dc + ch;
    float* Ob = out + (size_t)b * Lc * Dc + ch;
    const float* pvb = pv + b * STRIDE;
    const int* bpb = bpos + b * STRIDE;
    int n = nb[b];
    int ng = (n + G - 1) / G;

    float xA[G], pA[G]; int tA[G + 1];
    #pragma unroll
    for (int i = 0; i < G; ++i) {
        int t = bpb[i];
        tA[i] = t;
        pA[i] = pvb[i];
        xA[i] = (t < Lc) ? Hb[(size_t)t * Dc] : 0.0f;
    }
    tA[G] = bpb[G];

    float h = 0.0f;
    for (int g = 0; g < ng; ++g) {
        int nbase = (g + 1) * G;
        float xB[G], pB[G]; int tB[G + 1];
        #pragma unroll
        for (int i = 0; i < G; ++i) {
            int t = bpb[nbase + i];
            tB[i] = t;
            pB[i] = pvb[nbase + i];
            xB[i] = (t < Lc) ? Hb[(size_t)t * Dc] : 0.0f;
        }
        tB[G] = bpb[nbase + G];
        #pragma unroll
        for (int i = 0; i < G; ++i) {
            h = (1.0f - pA[i]) * h + pA[i] * xA[i];
            int te = tA[i + 1];
            for (int tt = tA[i]; tt < te; ++tt) Ob[(size_t)tt * Dc] = h;
        }
        #pragma unroll
        for (int i = 0; i < G; ++i) { xA[i] = xB[i]; pA[i] = pB[i]; tA[i] = tB[i]; }
        tA[G] = tB[G];
    }
}

extern "C" void kernel_launch(void* const* d_in, const int* in_sizes, int n_in,
                              void* d_out, int out_size, void* d_ws, size_t ws_size,
                              hipStream_t stream)
{
    const float* H  = (const float*)d_in[0];
    const float* Wq = (const float*)d_in[1];
    const float* Wk = (const float*)d_in[2];
    const float* lt = (const float*)d_in[3];
    const float* bb = (const float*)d_in[4];
    const int* mask = (const int*)d_in[5];
    float* out = (float*)d_out;

    char* ws = (char*)d_ws;
    char*  Hcv  = (char*)d_out;                  // staging in d_out; K3 overwrites
    char*  Wcv  = ws + WCV_OFF;
    float* part = (float*)(ws + PART_OFF);
    float* pv   = (float*)(ws + PV_OFF);
    int*   bpos = (int*)(ws + BPOS_OFF);
    int*   nbp  = (int*)(ws + NB_OFF);

    hipLaunchKernelGGL(k0_convert, dim3(((16384 + 2304) * 144 + 255) / 256),
                       dim3(256), 0, stream, H, Wq, Wk, Hcv, Wcv);
    hipLaunchKernelGGL(k1_mfma, dim3(NCHUNK * 128), dim3(256), 0, stream,
                       Hcv, Wcv, part);
    hipLaunchKernelGGL(k2_boundary, dim3(Bc), dim3(256), 0, stream,
                       part, lt, bb, mask, pv, bpos, nbp);
    hipLaunchKernelGGL(k3_ema, dim3(Bc, 18), dim3(64), 0, stream,
                       H, pv, bpos, nbp, out);
}

// Round 17
// 362.809 us; speedup vs baseline: 1.1064x; 1.0467x over previous
//
#include <hip/hip_runtime.h>
#include <hip/hip_bf16.h>
#include <cstdint>
#include <cstddef>

#define Bc 8
#define Lc 2048
#define Dc 1152
#define STRIDE 2080
#define G 8
#define NCHUNK 18            // e-chunks of 64

// ---- workspace layout (bytes) ----
#define WCV_OFF   0u
#define PART_OFF  10616832u
#define BL_OFF    17694720u
#define PV_OFF    17760256u
#define BPOS_OFF  17826816u
#define NB_OFF    17893376u

using bf16x8 = __attribute__((ext_vector_type(8))) short;
using f32x4  = __attribute__((ext_vector_type(4))) float;
#define MFMA(a, b, c) __builtin_amdgcn_mfma_f32_16x16x32_bf16(a, b, c, 0, 0, 0)

__device__ __forceinline__ void gld16(const void* g, void* l) {
    __builtin_amdgcn_global_load_lds(
        (const __attribute__((address_space(1))) void*)(g),
        (__attribute__((address_space(3))) void*)(l), 16, 0, 0);
}

__device__ __forceinline__ unsigned short bf_hi(float x) {
    __hip_bfloat16 h = __float2bfloat16(x);
    return *reinterpret_cast<unsigned short*>(&h);
}
__device__ __forceinline__ float bf_f(unsigned short u) {
    __hip_bfloat16 h; *reinterpret_cast<unsigned short*>(&h) = u;
    return __bfloat162float(h);
}

// ---------------- Kernel 0: fp32 -> bf16 hi/lo split, staged layout ----------------
__global__ __launch_bounds__(256) void k0_convert(
    const float* __restrict__ H, const float* __restrict__ Wq,
    const float* __restrict__ Wk, char* __restrict__ Hcv, char* __restrict__ Wcv)
{
    int idx = blockIdx.x * 256 + threadIdx.x;
    if (idx >= (16384 + 2304) * 144) return;
    int cchunk = idx & 3;
    int ks = (idx >> 2) % 36;
    int row = idx / 144;
    const float* src;
    char* dst;
    if (row < 16384) {
        src = H + (size_t)row * Dc;
        dst = Hcv + ((size_t)row * 36 + ks) * 128;
    } else {
        int e = row - 16384;
        src = (e < Dc) ? (Wq + (size_t)e * Dc) : (Wk + (size_t)(e - Dc) * Dc);
        dst = Wcv + ((size_t)e * 36 + ks) * 128;
    }
    const float* s = src + ks * 32 + cchunk * 8;
    unsigned int hw0 = 0, hw1 = 0, hw2 = 0, hw3 = 0;
    unsigned int lw0 = 0, lw1 = 0, lw2 = 0, lw3 = 0;
    #define CV(i, HW, LW, SH)                                                  \
    {                                                                          \
        float x = s[i];                                                        \
        unsigned short h = bf_hi(x);                                           \
        unsigned short lo = bf_hi(x - bf_f(h));                                \
        HW |= ((unsigned int)h) << (SH);                                       \
        LW |= ((unsigned int)lo) << (SH);                                      \
    }
    CV(0, hw0, lw0, 0) CV(1, hw0, lw0, 16) CV(2, hw1, lw1, 0) CV(3, hw1, lw1, 16)
    CV(4, hw2, lw2, 0) CV(5, hw2, lw2, 16) CV(6, hw3, lw3, 0) CV(7, hw3, lw3, 16)
    #undef CV
    uint4 hv; hv.x = hw0; hv.y = hw1; hv.z = hw2; hv.w = hw3;
    uint4 lv; lv.x = lw0; lv.y = lw1; lv.z = lw2; lv.w = lw3;
    *(uint4*)(dst + cchunk * 16) = hv;
    *(uint4*)(dst + 64 + cchunk * 16) = lv;
}

// ---------------- Kernel 1: 3-product bf16-split MFMA GEMM (r11, 216 us) ----------------
// Frozen optimum: 0.5 reads/MFMA, 68 VGPR + 64 AGPR, ~9.5 waves/CU, 0 bank
// conflicts, within ~5% of the LDS-traffic wall. r12 (dbuf), r13 (8-wave),
// r14 (R=4) all bench-refuted.
__global__ __launch_bounds__(256, 2) void k1_mfma(
    const char* __restrict__ Hcv, const char* __restrict__ Wcv,
    float* __restrict__ partial)
{
    __shared__ __align__(16) char LdsB[32896];   // H 129*128=16512 | W 128*128=16384
    const int tid = threadIdx.x;
    const int bid = blockIdx.x;
    const int x = bid & 7;               // XCD-local remap
    const int r = bid >> 3;
    const int g = x + 8 * (r / 18);
    const int j = r % 18;
    const int batch = g >> 4;
    const int mt = g & 15;
    const int t0 = 1 + mt * 128;
    const int rowbase = batch * Lc + t0 - 1;
    const int rowmax = batch * Lc + (Lc - 1);

    const char *hp0, *hpt, *wp0;
    {
        int row = tid >> 3;
        int ch = (tid & 7) ^ (row & 7);
        hp0 = Hcv + (size_t)(rowbase + row) * 4608 + (ch << 4);
        int gr2 = rowbase + 128; if (gr2 > rowmax) gr2 = rowmax;
        hpt = Hcv + (size_t)gr2 * 4608 + ((tid & 7) << 4);
        wp0 = Wcv + (size_t)(j * 64 + row) * 4608 + (ch << 4);
    }

    const int l = tid & 63;
    const int w = tid >> 6;
    const int rl = l & 15;
    const int c = l >> 4;

    const int sA = c ^ (rl & 7);
    const int sB = c ^ ((rl + 1) & 7);
    const int offAh = rl * 128 + (sA << 4);
    const int offAl = rl * 128 + ((sA ^ 4) << 4);
    const int offBh = (rl + 1) * 128 + (sB << 4);
    const int offBl = (rl + 1) * 128 + ((sB ^ 4) << 4);
    const char* Wb = LdsB + 16512;

    f32x4 q00{0,0,0,0}, q01{0,0,0,0}, q02{0,0,0,0}, q03{0,0,0,0};
    f32x4 q10{0,0,0,0}, q11{0,0,0,0}, q12{0,0,0,0}, q13{0,0,0,0};
    f32x4 k00{0,0,0,0}, k01{0,0,0,0}, k02{0,0,0,0}, k03{0,0,0,0};
    f32x4 k10{0,0,0,0}, k11{0,0,0,0}, k12{0,0,0,0}, k13{0,0,0,0};

    for (int ks = 0; ks < 36; ++ks) {
        gld16(hp0,           LdsB + tid * 16);
        gld16(hp0 + 147456,  LdsB + (tid + 256) * 16);
        gld16(hp0 + 294912,  LdsB + (tid + 512) * 16);
        gld16(hp0 + 442368,  LdsB + (tid + 768) * 16);
        if (tid < 8) gld16(hpt, LdsB + (1024 + tid) * 16);
        gld16(wp0,           LdsB + 16512 + tid * 16);
        gld16(wp0 + 147456,  LdsB + 16512 + (tid + 256) * 16);
        gld16(wp0 + 5308416, LdsB + 16512 + (tid + 512) * 16);
        gld16(wp0 + 5455872, LdsB + 16512 + (tid + 768) * 16);
        hp0 += 128; hpt += 128; wp0 += 128;
        __syncthreads();

        const char* hm0 = LdsB + (2 * w) * 2048;
        const char* hm1 = LdsB + (2 * w + 1) * 2048;
        bf16x8 a0h = *(const bf16x8*)(hm0 + offAh);
        bf16x8 a0l = *(const bf16x8*)(hm0 + offAl);
        bf16x8 b0h = *(const bf16x8*)(hm0 + offBh);
        bf16x8 b0l = *(const bf16x8*)(hm0 + offBl);
        bf16x8 a1h = *(const bf16x8*)(hm1 + offAh);
        bf16x8 a1l = *(const bf16x8*)(hm1 + offAl);
        bf16x8 b1h = *(const bf16x8*)(hm1 + offBh);
        bf16x8 b1l = *(const bf16x8*)(hm1 + offBl);

        #define FSTEP(f, QA0, QA1, KA0, KA1)                                   \
        {                                                                      \
            const char* wqb = Wb + (f) * 2048;                                 \
            bf16x8 wh = *(const bf16x8*)(wqb + offAh);                         \
            bf16x8 wl = *(const bf16x8*)(wqb + offAl);                         \
            QA0 = MFMA(a0h, wh, QA0); QA0 = MFMA(a0h, wl, QA0);                \
            QA0 = MFMA(a0l, wh, QA0);                                          \
            QA1 = MFMA(a1h, wh, QA1); QA1 = MFMA(a1h, wl, QA1);                \
            QA1 = MFMA(a1l, wh, QA1);                                          \
            const char* wkb = Wb + 8192 + (f) * 2048;                          \
            bf16x8 vh = *(const bf16x8*)(wkb + offAh);                         \
            bf16x8 vl = *(const bf16x8*)(wkb + offAl);                         \
            KA0 = MFMA(b0h, vh, KA0); KA0 = MFMA(b0h, vl, KA0);                \
            KA0 = MFMA(b0l, vh, KA0);                                          \
            KA1 = MFMA(b1h, vh, KA1); KA1 = MFMA(b1h, vl, KA1);                \
            KA1 = MFMA(b1l, vh, KA1);                                          \
            __builtin_amdgcn_sched_barrier(0);                                 \
        }
        FSTEP(0, q00, q10, k00, k10)
        FSTEP(1, q01, q11, k01, k11)
        FSTEP(2, q02, q12, k02, k12)
        FSTEP(3, q03, q13, k03, k13)
        #undef FSTEP
        __syncthreads();
    }

    #define EMIT(QA, QB, QC, QD, KA, KB, KC, KD, TROW)                         \
    {                                                                          \
        float qq = (QA)*(QA) + (QB)*(QB) + (QC)*(QC) + (QD)*(QD);              \
        float kk = (KA)*(KA) + (KB)*(KB) + (KC)*(KC) + (KD)*(KD);              \
        float qk = (QA)*(KA) + (QB)*(KB) + (QC)*(KC) + (QD)*(KD);              \
        qq += __shfl_xor(qq, 1, 64); qq += __shfl_xor(qq, 2, 64);              \
        qq += __shfl_xor(qq, 4, 64); qq += __shfl_xor(qq, 8, 64);              \
        kk += __shfl_xor(kk, 1, 64); kk += __shfl_xor(kk, 2, 64);              \
        kk += __shfl_xor(kk, 4, 64); kk += __shfl_xor(kk, 8, 64);              \
        qk += __shfl_xor(qk, 1, 64); qk += __shfl_xor(qk, 2, 64);              \
        qk += __shfl_xor(qk, 4, 64); qk += __shfl_xor(qk, 8, 64);              \
        if (rl == 0) {                                                         \
            int t = t0 + (TROW);                                               \
            if (t < Lc) {                                                      \
                size_t pidx = (((size_t)j * Bc + batch) * Lc + t) * 3;         \
                partial[pidx] = qq; partial[pidx + 1] = kk;                    \
                partial[pidx + 2] = qk;                                        \
            }                                                                  \
        }                                                                      \
    }
    EMIT(q00[0], q01[0], q02[0], q03[0], k00[0], k01[0], k02[0], k03[0], 32*w + c*4 + 0)
    EMIT(q00[1], q01[1], q02[1], q03[1], k00[1], k01[1], k02[1], k03[1], 32*w + c*4 + 1)
    EMIT(q00[2], q01[2], q02[2], q03[2], k00[2], k01[2], k02[2], k03[2], 32*w + c*4 + 2)
    EMIT(q00[3], q01[3], q02[3], q03[3], k00[3], k01[3], k02[3], k03[3], 32*w + c*4 + 3)
    EMIT(q10[0], q11[0], q12[0], q13[0], k10[0], k11[0], k12[0], k13[0], 32*w + 16 + c*4 + 0)
    EMIT(q10[1], q11[1], q12[1], q13[1], k10[1], k11[1], k12[1], k13[1], 32*w + 16 + c*4 + 1)
    EMIT(q10[2], q11[2], q12[2], q13[2], k10[2], k11[2], k12[2], k13[2], 32*w + 16 + c*4 + 2)
    EMIT(q10[3], q11[3], q12[3], q13[3], k10[3], k11[3], k12[3], k13[3], 32*w + 16 + c*4 + 3)
    #undef EMIT
}

// ---------------- Kernel 1b: deterministic chunk-reduce -> bl (64 blocks) ----------------
// Separate from k2 on purpose: 16384 threads for the strided partial reduce.
// r16's fusion into the 8-block k2 was latency-bound (+20 us).
__global__ __launch_bounds__(256) void k1b_reduce(
    const float* __restrict__ partial, const float* __restrict__ ltemp,
    const float* __restrict__ bbias, float* __restrict__ bl_out)
{
    int idx = blockIdx.x * 256 + threadIdx.x;   // batch*Lc + t
    if (idx >= Bc * Lc) return;
    int t = idx & (Lc - 1);
    if (t == 0) return;
    float qq = 0.f, kk = 0.f, qk = 0.f;
    #pragma unroll
    for (int cn = 0; cn < NCHUNK; ++cn) {
        size_t p = ((size_t)cn * Bc * Lc + idx) * 3;
        qq += partial[p];
        kk += partial[p + 1];
        qk += partial[p + 2];
    }
    float T = expf(ltemp[0]);
    T = fminf(fmaxf(T, 0.1f), 10.0f);
    float den = fmaxf(sqrtf(qq), 1e-12f) * fmaxf(sqrtf(kk), 1e-12f);
    bl_out[idx] = (1.0f - qk / den) * T + bbias[0];
}

// ---------------- Kernel 2: boundary decision + stable compaction ----------------
__global__ __launch_bounds__(256) void k2_boundary(
    const float* __restrict__ bl_in, const int* __restrict__ mask,
    float* __restrict__ pv, int* __restrict__ bpos, int* __restrict__ nb)
{
    int b = blockIdx.x;
    int tid = threadIdx.x;
    const float* blb = bl_in + b * Lc;
    const int* mb = mask + b * Lc;

    float blv[8]; int f[8];
    int t0 = tid * 8;
    int s = 0;
    #pragma unroll
    for (int i = 0; i < 8; ++i) {
        int t = t0 + i;
        float v = (t == 0) ? 10.0f : blb[t];
        blv[i] = v;
        f[i] = (v > 0.0f && mb[t] != 0) ? 1 : 0;
        s += f[i];
    }
    int lane = tid & 63, wv = tid >> 6;
    int sc = s;
    #pragma unroll
    for (int off = 1; off < 64; off <<= 1) {
        int o = __shfl_up(sc, off, 64);
        if (lane >= off) sc += o;
    }
    __shared__ int wsums[4];
    if (lane == 63) wsums[wv] = sc;
    __syncthreads();
    int woff = 0;
    #pragma unroll
    for (int w2 = 0; w2 < 4; ++w2) woff += (w2 < wv) ? wsums[w2] : 0;
    int excl = woff + sc - s;
    int total = wsums[0] + wsums[1] + wsums[2] + wsums[3];

    float* pvb = pv + b * STRIDE;
    int* bpb = bpos + b * STRIDE;
    int r = excl;
    #pragma unroll
    for (int i = 0; i < 8; ++i) {
        if (f[i]) {
            int t = t0 + i;
            float p;
            if (t == 0) {
                p = 1.0f;
            } else {
                p = 1.0f / (1.0f + expf(-2.0f * blv[i]));
                p = fminf(fmaxf(p, 1e-4f), 1.0f - 1e-4f);
            }
            bpb[r] = t;
            pvb[r] = p;
            r += 1;
        }
    }
    if (tid == 0) nb[b] = total;
    for (int q = total + tid; q < STRIDE; q += 256) { bpb[q] = Lc; pvb[q] = 0.0f; }
}

// ---------------- Kernel 3: EMA over boundary tokens + span expansion ----------------
// G=8 (G=16 spilled in r15), grid (8,18)x64 (r14's best-measured tail).
__global__ __launch_bounds__(64) void k3_ema(
    const float* __restrict__ H, const float* __restrict__ pv,
    const int* __restrict__ bpos, const int* __restrict__ nb,
    float* __restrict__ out)
{
    int b = blockIdx.x;
    int ch = blockIdx.y * 64 + threadIdx.x;
    const float* Hb = H + (size_t)b * Lc * Dc + ch;
    float* Ob = out + (size_t)b * Lc * Dc + ch;
    const float* pvb = pv + b * STRIDE;
    const int* bpb = bpos + b * STRIDE;
    int n = nb[b];
    int ng = (n + G - 1) / G;

    float xA[G], pA[G]; int tA[G + 1];
    #pragma unroll
    for (int i = 0; i < G; ++i) {
        int t = bpb[i];
        tA[i] = t;
        pA[i] = pvb[i];
        xA[i] = (t < Lc) ? Hb[(size_t)t * Dc] : 0.0f;
    }
    tA[G] = bpb[G];

    float h = 0.0f;
    for (int g = 0; g < ng; ++g) {
        int nbase = (g + 1) * G;
        float xB[G], pB[G]; int tB[G + 1];
        #pragma unroll
        for (int i = 0; i < G; ++i) {
            int t = bpb[nbase + i];
            tB[i] = t;
            pB[i] = pvb[nbase + i];
            xB[i] = (t < Lc) ? Hb[(size_t)t * Dc] : 0.0f;
        }
        tB[G] = bpb[nbase + G];
        #pragma unroll
        for (int i = 0; i < G; ++i) {
            h = (1.0f - pA[i]) * h + pA[i] * xA[i];
            int te = tA[i + 1];
            for (int tt = tA[i]; tt < te; ++tt) Ob[(size_t)tt * Dc] = h;
        }
        #pragma unroll
        for (int i = 0; i < G; ++i) { xA[i] = xB[i]; pA[i] = pB[i]; tA[i] = tB[i]; }
        tA[G] = tB[G];
    }
}

extern "C" void kernel_launch(void* const* d_in, const int* in_sizes, int n_in,
                              void* d_out, int out_size, void* d_ws, size_t ws_size,
                              hipStream_t stream)
{
    const float* H  = (const float*)d_in[0];
    const float* Wq = (const float*)d_in[1];
    const float* Wk = (const float*)d_in[2];
    const float* lt = (const float*)d_in[3];
    const float* bb = (const float*)d_in[4];
    const int* mask = (const int*)d_in[5];
    float* out = (float*)d_out;

    char* ws = (char*)d_ws;
    char*  Hcv  = (char*)d_out;                  // staging in d_out; K3 overwrites
    char*  Wcv  = ws + WCV_OFF;
    float* part = (float*)(ws + PART_OFF);
    float* bl   = (float*)(ws + BL_OFF);
    float* pv   = (float*)(ws + PV_OFF);
    int*   bpos = (int*)(ws + BPOS_OFF);
    int*   nbp  = (int*)(ws + NB_OFF);

    hipLaunchKernelGGL(k0_convert, dim3(((16384 + 2304) * 144 + 255) / 256),
                       dim3(256), 0, stream, H, Wq, Wk, Hcv, Wcv);
    hipLaunchKernelGGL(k1_mfma, dim3(NCHUNK * 128), dim3(256), 0, stream,
                       Hcv, Wcv, part);
    hipLaunchKernelGGL(k1b_reduce, dim3((Bc * Lc + 255) / 256), dim3(256), 0, stream,
                       part, lt, bb, bl);
    hipLaunchKernelGGL(k2_boundary, dim3(Bc), dim3(256), 0, stream,
                       bl, mask, pv, bpos, nbp);
    hipLaunchKernelGGL(k3_ema, dim3(Bc, 18), dim3(64), 0, stream,
                       H, pv, bpos, nbp, out);
}